// Round 2
// baseline (805.375 us; speedup 1.0000x reference)
//
#include <hip/hip_runtime.h>
#include <cstdint>
#include <cstddef>

// CIN: B=1024, M=40, D=64, HK=128. rows = B*D = 65536 (row = b*64 + d)
// Layer: y[r,h] = sum_{i,j} x[r,i] * xk[r,j] * W[i,j,h]
// GEMM view: A[r, i*J+j] = x[r,i]*xk[r,j]  (J=64 padded for layer1, 128 for 2/3)
//            Bmat[(i*J+j), h] = W[i,j,h]   (stored transposed [h][k], bf16 hi/lo)
// 3-term bf16 split: a*w ~= ah*wh + ah*wl + al*wh  (error ~3*2^-18 per term)

typedef __attribute__((ext_vector_type(4))) float f4v;
typedef __attribute__((ext_vector_type(8))) short s8v;

__device__ __forceinline__ unsigned short f2bf(float f){
  unsigned u = __float_as_uint(f);
  u += 0x7fffu + ((u >> 16) & 1u);      // round-to-nearest-even on bf16 boundary
  return (unsigned short)(u >> 16);
}

// ---------------- weight prep: split + transpose into ws ----------------
// ws layout (ushort units):
//  W0hi @ 0        [128][2560]   (k = i*64 + j, j<40 real else 0)
//  W0lo @ 327680
//  W1hi @ 655360   [128][5120]   (k = i*128 + j)
//  W1lo @ 1310720
//  W2hi @ 1966080
//  W2lo @ 2621440            total 3,276,800 ushorts = 6.55 MB
__global__ void prep_weights(const float* __restrict__ W0,
                             const float* __restrict__ W1,
                             const float* __restrict__ W2,
                             unsigned short* __restrict__ ws)
{
  const int total = 327680 + 655360 + 655360;
  for (int e = blockIdx.x * blockDim.x + threadIdx.x; e < total;
       e += gridDim.x * blockDim.x){
    float w; int hi, lo;
    if (e < 327680){
      int h = e / 2560, k = e % 2560;
      int i = k >> 6, j = k & 63;
      w = (j < 40) ? W0[(i*40 + j)*128 + h] : 0.f;   // W0[i][j][h]
      hi = e; lo = 327680 + e;
    } else if (e < 983040){
      int r = e - 327680;
      int h = r / 5120, k = r % 5120;
      w = W1[k*128 + h];                              // W1 flat: (i*128+j)*128+h = k*128+h
      hi = 655360 + r; lo = 1310720 + r;
    } else {
      int r = e - 983040;
      int h = r / 5120, k = r % 5120;
      w = W2[k*128 + h];
      hi = 1966080 + r; lo = 2621440 + r;
    }
    unsigned short hb = f2bf(w);
    float whf = __uint_as_float((unsigned)hb << 16);
    unsigned short lb = f2bf(w - whf);
    ws[hi] = hb; ws[lo] = lb;
  }
}

// ---------------- main fused kernel ----------------
// block: 512 threads = 8 waves, 256 rows (4 b-values * 64 d), all 128 cols.
// wave tile: 64 rows x 64 cols (rgi = wave>>1 selects rows, cgi = wave&1 cols).
// LDS: xk[256][128] f32, XOR-swizzled: word(row,j) = row*128 + (j ^ ((row&7)<<2))

template<int J, int KT>
__device__ __forceinline__ void run_layer(
    const unsigned short* __restrict__ Whi,
    const unsigned short* __restrict__ Wlo,
    const float* __restrict__ xg,
    float* xk, float* __restrict__ out,
    int layerOff, int blockRow, int tid)
{
  const int lane = tid & 63;
  const int wv   = tid >> 6;
  const int cgi  = wv & 1, rgi = wv >> 1;
  const int lrow = lane & 15, q = lane >> 4;

  f4v acc[4][4];
#pragma unroll
  for (int a = 0; a < 4; a++)
#pragma unroll
    for (int b = 0; b < 4; b++)
      acc[a][b] = (f4v){0.f, 0.f, 0.f, 0.f};

  // per-ntile W row pointers (col = h index), each lane reads 16B at k0+q*8
  const unsigned short* wp[4];
  const unsigned short* wq[4];
#pragma unroll
  for (int nt = 0; nt < 4; nt++){
    int col = cgi*64 + nt*16 + lrow;
    wp[nt] = Whi + (size_t)col * KT + q*8;
    wq[nt] = Wlo + (size_t)col * KT + q*8;
  }

#pragma unroll 1
  for (int i = 0; i < 40; i++){
    float x0[4];
#pragma unroll
    for (int rt = 0; rt < 4; rt++){
      int gr = blockRow + rgi*64 + rt*16 + lrow;     // global row = b*64+d
      x0[rt] = xg[((gr >> 6)*40 + i)*64 + (gr & 63)]; // x[b][i][d]
    }
#pragma unroll
    for (int jb = 0; jb < J/32; jb++){
      const int k0 = i*J + jb*32;
      s8v bh[4], bl[4];
#pragma unroll
      for (int nt = 0; nt < 4; nt++){
        bh[nt] = *(const s8v*)(wp[nt] + k0);
        bl[nt] = *(const s8v*)(wq[nt] + k0);
      }
#pragma unroll
      for (int rt = 0; rt < 4; rt++){
        int row = rgi*64 + rt*16 + lrow;
        int w0 = row*128 + ((jb*32 + q*8) ^ ((row & 7) << 2));
        f4v v0 = *(const f4v*)(xk + w0);
        f4v v1 = *(const f4v*)(xk + (w0 ^ 4));
        float s = x0[rt];
        float a0 = s*v0[0], a1 = s*v0[1], a2 = s*v0[2], a3 = s*v0[3];
        float a4 = s*v1[0], a5 = s*v1[1], a6 = s*v1[2], a7 = s*v1[3];
        unsigned ah01, ah23, ah45, ah67, al01, al23, al45, al67;
        asm("v_cvt_pk_bf16_f32 %0, %1, %2" : "=v"(ah01) : "v"(a0), "v"(a1));
        asm("v_cvt_pk_bf16_f32 %0, %1, %2" : "=v"(ah23) : "v"(a2), "v"(a3));
        asm("v_cvt_pk_bf16_f32 %0, %1, %2" : "=v"(ah45) : "v"(a4), "v"(a5));
        asm("v_cvt_pk_bf16_f32 %0, %1, %2" : "=v"(ah67) : "v"(a6), "v"(a7));
        float r0 = a0 - __uint_as_float(ah01 << 16);
        float r1 = a1 - __uint_as_float(ah01 & 0xffff0000u);
        float r2 = a2 - __uint_as_float(ah23 << 16);
        float r3 = a3 - __uint_as_float(ah23 & 0xffff0000u);
        float r4 = a4 - __uint_as_float(ah45 << 16);
        float r5 = a5 - __uint_as_float(ah45 & 0xffff0000u);
        float r6 = a6 - __uint_as_float(ah67 << 16);
        float r7 = a7 - __uint_as_float(ah67 & 0xffff0000u);
        asm("v_cvt_pk_bf16_f32 %0, %1, %2" : "=v"(al01) : "v"(r0), "v"(r1));
        asm("v_cvt_pk_bf16_f32 %0, %1, %2" : "=v"(al23) : "v"(r2), "v"(r3));
        asm("v_cvt_pk_bf16_f32 %0, %1, %2" : "=v"(al45) : "v"(r4), "v"(r5));
        asm("v_cvt_pk_bf16_f32 %0, %1, %2" : "=v"(al67) : "v"(r6), "v"(r7));
        union { unsigned u[4]; s8v v; } Ah, Al;
        Ah.u[0]=ah01; Ah.u[1]=ah23; Ah.u[2]=ah45; Ah.u[3]=ah67;
        Al.u[0]=al01; Al.u[1]=al23; Al.u[2]=al45; Al.u[3]=al67;
#pragma unroll
        for (int nt = 0; nt < 4; nt++){
          acc[rt][nt] = __builtin_amdgcn_mfma_f32_16x16x32_bf16(Ah.v, bh[nt], acc[rt][nt], 0, 0, 0);
          acc[rt][nt] = __builtin_amdgcn_mfma_f32_16x16x32_bf16(Ah.v, bl[nt], acc[rt][nt], 0, 0, 0);
          acc[rt][nt] = __builtin_amdgcn_mfma_f32_16x16x32_bf16(Al.v, bh[nt], acc[rt][nt], 0, 0, 0);
        }
      }
    }
  }
  __syncthreads();              // all reads of old xk done
  // C/D layout (verified): col = lane&15, row = (lane>>4)*4 + reg
#pragma unroll
  for (int rt = 0; rt < 4; rt++){
#pragma unroll
    for (int nt = 0; nt < 4; nt++){
      int col = cgi*64 + nt*16 + lrow;
#pragma unroll
      for (int r = 0; r < 4; r++){
        int row = rgi*64 + rt*16 + q*4 + r;
        xk[row*128 + (col ^ ((row & 7) << 2))] = acc[rt][nt][r];
      }
    }
  }
  __syncthreads();              // new xk visible
  // sum-pool over d: out[b, layerOff+h] = sum_d Y[(b,d),h]
  {
    int b_l = tid >> 7, h = tid & 127;   // 4 x 128 = 512 threads
    float sum = 0.f;
#pragma unroll 8
    for (int d = 0; d < 64; d++){
      int row = b_l*64 + d;
      sum += xk[row*128 + (h ^ ((row & 7) << 2))];
    }
    out[(size_t)(blockRow/64 + b_l)*384 + layerOff + h] = sum;
  }
}

__global__ __launch_bounds__(512, 2) void cin_main(
    const float* __restrict__ xg,
    const unsigned short* __restrict__ wsbase,
    float* __restrict__ out)
{
  extern __shared__ float xk[];          // [256][128] f32, swizzled, 128 KiB
  const int tid = threadIdx.x;
  const int blockRow = blockIdx.x * 256;

  // stage x (zero-padded to j<64) into xk for layer 1
#pragma unroll 1
  for (int it = 0; it < 32; it++){
    int idx = it*512 + tid;
    int row = idx & 255, j = idx >> 8;   // j in [0,64)
    int gr = blockRow + row;
    float v = 0.f;
    if (j < 40) v = xg[((gr >> 6)*40 + j)*64 + (gr & 63)];
    xk[row*128 + (j ^ ((row & 7) << 2))] = v;
  }
  __syncthreads();

  run_layer< 64, 2560>(wsbase,           wsbase + 327680,  xg, xk, out,   0, blockRow, tid);
  run_layer<128, 5120>(wsbase + 655360,  wsbase + 1310720, xg, xk, out, 128, blockRow, tid);
  run_layer<128, 5120>(wsbase + 1966080, wsbase + 2621440, xg, xk, out, 256, blockRow, tid);
}

extern "C" void kernel_launch(void* const* d_in, const int* in_sizes, int n_in,
                              void* d_out, int out_size, void* d_ws, size_t ws_size,
                              hipStream_t stream)
{
  (void)in_sizes; (void)n_in; (void)out_size; (void)ws_size;
  const float* x  = (const float*)d_in[0];
  const float* W0 = (const float*)d_in[1];
  const float* W1 = (const float*)d_in[2];
  const float* W2 = (const float*)d_in[3];
  float* out = (float*)d_out;
  unsigned short* ws = (unsigned short*)d_ws;   // needs 6,553,600 bytes

  // allow 128 KiB dynamic LDS (idempotent, not a stream op -> capture-safe)
  hipFuncSetAttribute((const void*)cin_main,
                      hipFuncAttributeMaxDynamicSharedMemorySize, 131072);

  prep_weights<<<2048, 256, 0, stream>>>(W0, W1, W2, ws);
  cin_main<<<256, 512, 131072, stream>>>(x, ws, out);
}